// Round 11
// baseline (4492.981 us; speedup 1.0000x reference)
//
#include <hip/hip_runtime.h>
#include <hip/hip_bf16.h>

typedef unsigned short u16;
typedef unsigned char u8;
typedef unsigned int u32;
typedef unsigned long long u64;
typedef __attribute__((ext_vector_type(8))) short short8;
typedef __attribute__((ext_vector_type(8))) u16 ushort8;
typedef __attribute__((ext_vector_type(4))) float f32x4;
typedef __attribute__((ext_vector_type(2))) float f32x2;

__device__ __forceinline__ float bf2f(u16 x){ u32 u=((u32)x)<<16; return __builtin_bit_cast(float,u); }
__device__ __forceinline__ u16 f2bf(float f){ u32 u=__builtin_bit_cast(u32,f); u32 r=(u+0x7fffu+((u>>16)&1u))>>16; return (u16)r; }
__device__ __forceinline__ float sigf(float x){ return 1.f/(1.f+__expf(-x)); }

// coherent STORES only (write-through past L2). Loads are plain; correctness
// from first-touch-after-write (time-indexed buffers).
__device__ __forceinline__ void scf(float* p, float v){
  __hip_atomic_store(p, v, __ATOMIC_RELAXED, __HIP_MEMORY_SCOPE_AGENT);
}
__device__ __forceinline__ void scu16(u16* p, u16 v){
  __hip_atomic_store(p, v, __ATOMIC_RELAXED, __HIP_MEMORY_SCOPE_AGENT);
}
__device__ __forceinline__ int ald(const int* p){
  return __hip_atomic_load(p, __ATOMIC_RELAXED, __HIP_MEMORY_SCOPE_AGENT);
}
__device__ __forceinline__ void aadd(int* p){
  __hip_atomic_fetch_add(p, 1, __ATOMIC_RELAXED, __HIP_MEMORY_SCOPE_AGENT);
}

// ---------------- prologue kernels ----------------

__global__ __launch_bounds__(256) void k_cast(const float* __restrict__ s, u16* __restrict__ d, long n){
  long i = ((long)blockIdx.x*256 + threadIdx.x)*8;
  if (i >= n) return;
  float4 a = *(const float4*)(s+i);
  float4 b = *(const float4*)(s+i+4);
  ushort8 o;
  o[0]=f2bf(a.x); o[1]=f2bf(a.y); o[2]=f2bf(a.z); o[3]=f2bf(a.w);
  o[4]=f2bf(b.x); o[5]=f2bf(b.y); o[6]=f2bf(b.z); o[7]=f2bf(b.w);
  *(ushort8*)(d+i) = o;
}

// f32 -> OCP e4m3 fp8 (HW cvt)
__global__ __launch_bounds__(256) void k_cast8(const float* __restrict__ s, u8* __restrict__ d, long n){
  long i = ((long)blockIdx.x*256 + threadIdx.x)*8;
  if (i >= n) return;
  float4 a = *(const float4*)(s+i);
  float4 b = *(const float4*)(s+i+4);
  u32 w0 = 0, w1 = 0;
  w0 = __builtin_amdgcn_cvt_pk_fp8_f32(a.x, a.y, w0, false);
  w0 = __builtin_amdgcn_cvt_pk_fp8_f32(a.z, a.w, w0, true);
  w1 = __builtin_amdgcn_cvt_pk_fp8_f32(b.x, b.y, w1, false);
  w1 = __builtin_amdgcn_cvt_pk_fp8_f32(b.z, b.w, w1, true);
  uint2 o; o.x = w0; o.y = w1;
  *(uint2*)(d+i) = o;
}

// x-layout: [a_e(0..511) | t_e(512..767) | att(768..1791) | h(1792..2815)]
__global__ __launch_bounds__(256) void k_build_wc(const float* __restrict__ Wih, const float* __restrict__ Whh,
                                                  u16* __restrict__ WC){
  long i8 = (long)blockIdx.x*256 + threadIdx.x;           // 4096*352
  if (i8 >= (long)4096*352) return;
  int j = (int)(i8/352); int kk = (int)(i8%352)*8;
  const float* src;
  if (kk < 512)        src = Wih + (long)j*1792 + kk;
  else if (kk < 768)   src = Wih + (long)j*1792 + (kk+1024);
  else if (kk < 1792)  src = Wih + (long)j*1792 + (kk-256);
  else                 src = Whh + (long)j*1024 + (kk-1792);
  u16* dst = WC + (long)j*2816 + kk;
  ushort8 o;
  #pragma unroll
  for (int q=0;q<8;++q) o[q] = f2bf(src[q]);
  *(ushort8*)dst = o;
}

__global__ __launch_bounds__(256) void k_wattT(const float* __restrict__ Wa, u16* __restrict__ WT){
  int id = blockIdx.x*256 + threadIdx.x;                  // 1M
  int m = id >> 10, k = id & 1023;
  WT[(long)m*1024 + k] = f2bf(Wa[(long)k*1024 + m]);
}

// mean over S from the original f32 enc
__global__ __launch_bounds__(256) void k_meanf(const float* __restrict__ enc, u16* __restrict__ MEANB){
  int b = blockIdx.x, h = blockIdx.y*256 + threadIdx.x;
  const float* p = enc + ((long)b<<20) + h;
  float s = 0.f;
  for (int ss=0; ss<1024; ++ss) s += p[(long)ss<<10];
  MEANB[b*1024 + h] = f2bf(s * (1.f/1024.f));
}

__global__ __launch_bounds__(256) void k_embed(const float* __restrict__ pemb, const float* __restrict__ temb,
      const int* __restrict__ pid, const int* __restrict__ tid_, const int* __restrict__ slen,
      u16* __restrict__ XC){
  int t = blockIdx.x >> 6, b = blockIdx.x & 63;
  bool valid = (t>0) && (t < slen[b]);
  int pi = pid[b*64 + t], ti = tid_[b*64 + t];
  u16* dst = XC + (long)blockIdx.x*2816;
  for (int kk = threadIdx.x; kk < 768; kk += 256){
    float v = 0.f;
    if (valid) v = (kk<512) ? pemb[(long)pi*512 + kk] : temb[(long)ti*256 + (kk-512)];
    dst[kk] = f2bf(v);
  }
}

// generic small GEMM: out = A[M x K] @ W[N x K]^T (block: 64 rows x 16 cols, 4 waves)
template<int MODE>
__global__ __launch_bounds__(256) void k_gemm(const u16* __restrict__ A, long lda,
      const u16* __restrict__ W, int K, const float* __restrict__ bias,
      float* __restrict__ OF, long ldo, u16* __restrict__ OB1, long ldb1){
  int l = threadIdx.x & 63, w = threadIdx.x >> 6;
  int c = l & 15, g = l >> 4;
  int n0 = blockIdx.x*16, m0 = blockIdx.y*64;
  const u16* ap = A + (long)(m0 + w*16 + c)*lda + g*8;
  const u16* bp = W + (long)(n0 + c)*K + g*8;
  f32x4 acc = {0.f,0.f,0.f,0.f};
  int kit = K >> 5;
  #pragma unroll 4
  for (int kb=0; kb<kit; ++kb){
    short8 av = *(const short8*)(ap + kb*32);
    short8 bv = *(const short8*)(bp + kb*32);
    acc = __builtin_amdgcn_mfma_f32_16x16x32_bf16(av, bv, acc, 0, 0, 0);
  }
  #pragma unroll
  for (int r=0;r<4;++r){
    int row = m0 + w*16 + g*4 + r;
    int col = n0 + c;
    float v = acc[r];
    if (MODE==2){ OB1[(long)row*ldb1 + col] = f2bf(tanhf(v + bias[col])); }
    if (MODE==3){ OF[(long)row*ldo + col] = v + bias[col]; }
  }
}

__global__ __launch_bounds__(256) void k_loss(const float* __restrict__ LG, const int* __restrict__ tgt,
      const int* __restrict__ slen, float* __restrict__ out){
  int b = blockIdx.x;
  int w = threadIdx.x >> 6, l = threadIdx.x & 63;
  int len = slen[b];
  float accum = 0.f;
  for (int t = w; t < 64; t += 4){
    if (t >= len) continue;
    const float* lp = LG + ((long)(t*64 + b))*256;
    float v0=lp[l], v1=lp[l+64], v2=lp[l+128], v3=lp[l+192];
    float mx = fmaxf(fmaxf(v0,v1), fmaxf(v2,v3));
    #pragma unroll
    for (int off=32; off; off>>=1) mx = fmaxf(mx, __shfl_xor(mx, off));
    float s = __expf(v0-mx)+__expf(v1-mx)+__expf(v2-mx)+__expf(v3-mx);
    #pragma unroll
    for (int off=32; off; off>>=1) s += __shfl_xor(s, off);
    float ltg = lp[tgt[b*64 + t]];
    float p = __expf(ltg - mx)/s;
    accum += logf(p + 1e-8f);
  }
  __shared__ float sm[4];
  if (l == 0) sm[w] = accum;
  __syncthreads();
  if (threadIdx.x == 0) out[b] = sm[0]+sm[1]+sm[2]+sm[3];
}

// ---------------- persistent decoder (256 blocks x 1024 threads) ----------------
// ENC pinned in registers (er[12] = 192 rows/block; overflow rows streamed).
// Flags: F1/F4 global (16 group counters, wave0 lane-parallel poll);
// F2/F3/F3c group-scoped (b-group granularity) for partial overlap.

__global__ __launch_bounds__(1024,1) void k_decoder(
      const u8* __restrict__ ENC8, const u16* __restrict__ WC,
      const u16* __restrict__ WAVT, const u16* __restrict__ WAVEC,
      const float* __restrict__ bih, const float* __restrict__ bhh,
      u16* __restrict__ XC, u16* __restrict__ ATT,
      float* __restrict__ HWT, float* __restrict__ PLT,
      u16* __restrict__ CTXBT, u16* __restrict__ CTXFT,
      const int* __restrict__ src_lens, int* __restrict__ BAR){
  const int tid = threadIdx.x;
  const int w = tid >> 6, l = tid & 63, c = l & 15, g = l >> 4;
  const int bx = blockIdx.x;

  __shared__ float smem[12320];                 // 48.1KB, phase-aliased
  f32x4* lacc  = (f32x4*)smem;                  // P1/P2: [16][64] f32x4
  float* s_ctx = smem;                          // P3: [8][1024]
  float* s_ls  = smem + 12288;                  // [16]
  u16*   ldsc  = (u16*)smem;                    // P4: [16][1024] bf16
  f32x4* lacc4 = (f32x4*)(smem + 8192);         // P4: [16][64] f32x4

  int* F1  = BAR;                               // 16 counters, stride 16 ints
  int* F4  = BAR + 256;
  int* F2  = BAR + 512;                         // 4 counters
  int* F3  = BAR + 576;
  int* F3c = BAR + 640;

  // P1 constants
  const int n0 = bx << 2;
  const int jrow = n0 + (c & 3) + ((c >> 2) << 10);
  const float biasj = bih[jrow] + bhh[jrow];
  const int kh = w >> 2, mt = w & 3;
  const int lbase = l & 0x33;
  float creg[4] = {0.f,0.f,0.f,0.f};
  // P2 constants
  const int mt2 = bx & 3, nt2 = bx >> 2;
  // P3 constants (fixed 4 chunks per b)
  const int b3 = bx >> 2, ci3 = bx & 3;
  int len3 = src_lens[b3]; if (len3 < 1) len3 = 1; if (len3 > 1024) len3 = 1024;
  const int chunk3 = (len3 + 3) >> 2;
  int s0 = ci3*chunk3;
  int s1 = s0 + chunk3; if (s1 > len3) s1 = len3;
  const u8* encb = ENC8 + (((long)b3)<<20);
  int lim = s1 - s0 - w;
  int nqv = (lim <= 0) ? 0 : ((lim + 15) >> 4);
  if (nqv > 16) nqv = 16;
  // P4 constants
  const int mt4 = bx & 3, nt4 = bx >> 2;
  const int grp = bx & 15;

  // ---- pin ENC chunk rows (q<12) in registers ----
  uint4 er[12];
  #pragma unroll
  for (int q=0;q<12;++q){
    int r = s0 + q*16 + w;
    if (r >= s1) r = s0;
    er[q] = *(const uint4*)(encb + ((long)r<<10) + l*16);
  }

  for (int t = 0; t < 64; ++t){
    const int gen = t + 1;
    const u16* XCt = XC + (size_t)t*64*2816;
    u16* XCn = XC + (size_t)(t+1)*64*2816;
    const u16* Hcur = XCn + 1792;
    float* HW   = HWT  + ((size_t)t<<16);
    float* PL   = PLT  + ((size_t)t<<8);
    u16*  CTXB  = CTXBT + ((size_t)t<<18);
    u16*  CTXF  = CTXFT + ((size_t)t<<16);

    // ---- P1: gates GEMM (split-K x4) + LSTM pointwise; h -> XCn ----
    {
      const u16* ap = XCt + (long)(mt*16 + c)*2816 + kh*704 + g*8;
      const u16* bp = WC  + (long)jrow*2816 + kh*704 + g*8;
      f32x4 acc = {0.f,0.f,0.f,0.f};
      #pragma unroll 11
      for (int kb=0; kb<22; ++kb){
        short8 av = *(const short8*)(ap + kb*32);
        short8 bv = *(const short8*)(bp + kb*32);
        acc = __builtin_amdgcn_mfma_f32_16x16x32_bf16(av, bv, acc, 0, 0, 0);
      }
      lacc[w*64 + l] = acc;
      __syncthreads();
      if (w < 4){
        f32x4 a0 = lacc[w*64 + l];
        f32x4 a1 = lacc[(w+4)*64 + l];
        f32x4 a2 = lacc[(w+8)*64 + l];
        f32x4 a3 = lacc[(w+12)*64 + l];
        #pragma unroll
        for (int r=0;r<4;++r){
          float val = a0[r] + a1[r] + a2[r] + a3[r] + biasj;
          float iv = __shfl(val, lbase);
          float fv = __shfl(val, lbase+4);
          float gv = __shfl(val, lbase+8);
          float ov = __shfl(val, lbase+12);
          if ((l & 12) == 0){
            float cn = sigf(fv)*creg[r] + sigf(iv)*tanhf(gv);
            float hn = sigf(ov)*tanhf(cn);
            creg[r] = cn;
            int b = w*16 + g*4 + r;
            int n = n0 + (l & 3);
            scu16(XCn + (long)b*2816 + 1792 + n, f2bf(hn));
          }
        }
      }
    }
    __syncthreads();
    if (tid == 0) aadd(F1 + grp*16);
    if (tid < 64){
      const int* pf = F1 + (tid & 15)*16;
      int tgt = gen*16;
      for(;;){
        int v = ald(pf);
        if (__all(v >= tgt)) break;
        __builtin_amdgcn_s_sleep(1);
      }
    }
    __syncthreads();

    // ---- P2: HW = h @ W_att^T (16-way split-K, LDS reduce) ----
    {
      const u16* ap = Hcur + (long)(mt2*16 + c)*2816 + w*64 + g*8;
      const u16* bp = WAVT + (long)(nt2*16 + c)*1024 + w*64 + g*8;
      f32x4 acc = {0.f,0.f,0.f,0.f};
      #pragma unroll
      for (int kb=0; kb<2; ++kb){
        short8 av = *(const short8*)(ap + kb*32);
        short8 bv = *(const short8*)(bp + kb*32);
        acc = __builtin_amdgcn_mfma_f32_16x16x32_bf16(av, bv, acc, 0, 0, 0);
      }
      lacc[w*64 + l] = acc;
      __syncthreads();
      if (w == 0){
        f32x4 rd = lacc[l];
        #pragma unroll
        for (int w2=1; w2<16; ++w2) rd += lacc[w2*64 + l];
        #pragma unroll
        for (int r=0;r<4;++r)
          scf(HW + (long)(mt2*16 + g*4 + r)*1024 + nt2*16 + c, rd[r]);
      }
    }
    __syncthreads();
    if (tid == 0){
      aadd(F2 + mt2*16);
      while (ald(F2 + (bx>>6)*16) < gen*64) __builtin_amdgcn_s_sleep(1);
    }
    __syncthreads();

    // ---- P3: attention from REGISTERS (max-free exp) ----
    {
      float hw[16], ctx[16];
      const float* hwp = HW + b3*1024 + l*16;
      #pragma unroll
      for (int jj=0;jj<4;++jj){
        float4 v = *(const float4*)(hwp + jj*4);
        hw[4*jj]=v.x; hw[4*jj+1]=v.y; hw[4*jj+2]=v.z; hw[4*jj+3]=v.w;
      }
      #pragma unroll
      for (int jj=0;jj<16;++jj) ctx[jj]=0.f;
      float lsum = 0.f;
      auto proc = [&](uint4 ev){
        float e[16];
        #pragma unroll
        for (int jj=0;jj<4;++jj){
          u32 x = ((const u32*)&ev)[jj];
          f32x2 lo = __builtin_amdgcn_cvt_pk_f32_fp8(x, false);
          f32x2 hi = __builtin_amdgcn_cvt_pk_f32_fp8(x, true);
          e[4*jj]=lo[0]; e[4*jj+1]=lo[1]; e[4*jj+2]=hi[0]; e[4*jj+3]=hi[1];
        }
        float sc = 0.f;
        #pragma unroll
        for (int jj=0;jj<16;++jj) sc += e[jj]*hw[jj];
        #pragma unroll
        for (int off=32; off; off>>=1) sc += __shfl_xor(sc, off);
        float pe = __expf(sc);
        lsum += pe;
        #pragma unroll
        for (int jj=0;jj<16;++jj) ctx[jj] += pe*e[jj];
      };
      #pragma unroll
      for (int q=0;q<12;++q) if (q < nqv) proc(er[q]);
      for (int q=12; q<nqv; ++q){
        uint4 ev = *(const uint4*)(encb + ((long)(s0 + q*16 + w)<<10) + l*16);
        proc(ev);
      }
      if (l == 0) s_ls[w] = lsum;
      if (w < 8){
        #pragma unroll
        for (int jj=0;jj<16;++jj) s_ctx[w*1024 + l*16 + jj] = ctx[jj];
      }
      __syncthreads();
      if (w >= 8){
        #pragma unroll
        for (int jj=0;jj<16;++jj) s_ctx[(w-8)*1024 + l*16 + jj] += ctx[jj];
      }
      __syncthreads();
      {
        float v = 0.f;
        #pragma unroll
        for (int p=0;p<8;++p) v += s_ctx[p*1024 + tid];
        scu16(CTXB + (((long)bx)<<10) + tid, f2bf(v));
      }
      if (tid == 0){
        float L = 0.f;
        #pragma unroll
        for (int q=0;q<16;++q) L += s_ls[q];
        scf(PL + bx, L);
      }
    }
    __syncthreads();
    if (tid == 0) aadd(F3 + (bx>>6)*16);

    // ---- combine phase: blocks 0..63 finalize ctx for b=bx ----
    if (bx < 64){
      if (tid == 0){
        while (ald(F3 + (bx>>4)*16) < gen*64) __builtin_amdgcn_s_sleep(1);
      }
      __syncthreads();
      int b = bx;
      float L = PL[b*4] + PL[b*4+1] + PL[b*4+2] + PL[b*4+3];
      float inv = (L > 0.f) ? 1.f/L : 0.f;
      const u16* c0 = CTXB + (long)(b*4+0)*1024;
      const u16* c1 = CTXB + (long)(b*4+1)*1024;
      const u16* c2 = CTXB + (long)(b*4+2)*1024;
      const u16* c3 = CTXB + (long)(b*4+3)*1024;
      float v = bf2f(c0[tid]) + bf2f(c1[tid]) + bf2f(c2[tid]) + bf2f(c3[tid]);
      scu16(CTXF + (long)b*1024 + tid, f2bf(v*inv));
      __syncthreads();
      if (tid == 0) aadd(F3c + (bx>>4)*16);
    }
    if (tid == 0){
      while (ald(F3c + mt4*16) < gen*16) __builtin_amdgcn_s_sleep(1);
    }
    __syncthreads();

    // ---- P4: stage final ctx -> LDS swz + att = tanh([h|ctx]@W_attvec^T) ----
    {
      const int b16 = w;                        // 16 rows
      const u16* cf = CTXF + (long)(mt4*16 + b16)*1024;
      ushort8 v0 = *(const ushort8*)(cf + l*8);
      ushort8 v1 = *(const ushort8*)(cf + (l+64)*8);
      const int swz = (b16 & 7) << 3;
      *(ushort8*)(ldsc + ((b16*1024 + l*8) ^ swz)) = v0;
      *(ushort8*)(ldsc + ((b16*1024 + (l+64)*8) ^ swz)) = v1;
      __syncthreads();
      f32x4 acc = {0.f,0.f,0.f,0.f};
      const int koff = (w < 8) ? w*128 : 1024 + (w-8)*128;
      const u16* bp = WAVEC + (long)(nt4*16 + c)*2048 + koff + g*8;
      if (w < 8){
        const u16* ap = Hcur + (long)(mt4*16 + c)*2816 + w*128 + g*8;
        #pragma unroll
        for (int kb=0; kb<4; ++kb){
          short8 av = *(const short8*)(ap + kb*32);
          short8 bv = *(const short8*)(bp + kb*32);
          acc = __builtin_amdgcn_mfma_f32_16x16x32_bf16(av, bv, acc, 0, 0, 0);
        }
      } else {
        const int cswz = (c & 7) << 3;
        const int kbase = c*1024 + (w-8)*128 + g*8;
        #pragma unroll
        for (int kb=0; kb<4; ++kb){
          short8 av = *(const short8*)(ldsc + ((kbase + kb*32) ^ cswz));
          short8 bv = *(const short8*)(bp + kb*32);
          acc = __builtin_amdgcn_mfma_f32_16x16x32_bf16(av, bv, acc, 0, 0, 0);
        }
      }
      lacc4[w*64 + l] = acc;
      __syncthreads();
      if (w == 0){
        f32x4 rd = lacc4[l];
        #pragma unroll
        for (int w2=1; w2<16; ++w2) rd += lacc4[w2*64 + l];
        #pragma unroll
        for (int r=0;r<4;++r){
          int b_ = mt4*16 + g*4 + r;
          int col = nt4*16 + c;
          u16 x = f2bf(tanhf(rd[r]));
          scu16(XCn + (long)b_*2816 + 768 + col, x);
          ATT[((long)t*64 + b_)*1024 + col] = x;
        }
      }
    }
    __syncthreads();
    if (tid == 0) aadd(F4 + grp*16);
    if (tid < 64){
      const int* pf = F4 + (tid & 15)*16;
      int tgt = gen*16;
      for(;;){
        int v = ald(pf);
        if (__all(v >= tgt)) break;
        __builtin_amdgcn_s_sleep(1);
      }
    }
    __syncthreads();
  }
}

extern "C" void kernel_launch(void* const* d_in, const int* in_sizes, int n_in,
                              void* d_out, int out_size, void* d_ws, size_t ws_size,
                              hipStream_t stream){
  const float* enc      = (const float*)d_in[0];
  const float* W_ih     = (const float*)d_in[1];
  const float* b_ih     = (const float*)d_in[2];
  const float* W_hh     = (const float*)d_in[3];
  const float* b_hh     = (const float*)d_in[4];
  const float* W_att    = (const float*)d_in[5];
  const float* W_attvec = (const float*)d_in[6];
  const float* W_init   = (const float*)d_in[7];
  const float* b_init   = (const float*)d_in[8];
  const float* W_q2a    = (const float*)d_in[9];
  const float* b_q2a    = (const float*)d_in[10];
  const float* prod_emb = (const float*)d_in[11];
  const float* prod_bias= (const float*)d_in[12];
  const float* type_emb = (const float*)d_in[13];
  const int* prev_pid   = (const int*)d_in[14];
  const int* prev_tid   = (const int*)d_in[15];
  const int* target     = (const int*)d_in[16];
  const int* sk_lens    = (const int*)d_in[17];
  const int* src_lens   = (const int*)d_in[18];
  float* out = (float*)d_out;

  char* ws = (char*)d_ws;
  size_t o = 0;
  auto alloc = [&](size_t bytes)->char*{ char* p = ws + o; o += (bytes + 255) & ~(size_t)255; return p; };
  u8*   ENC8 = (u8*)alloc((size_t)64*1024*1024);      // 64MB fp8
  u16*  WC   = (u16*)alloc((size_t)4096*2816*2);      // 22.5MB
  u16*  WAVT = (u16*)alloc((size_t)1024*1024*2);
  u16*  WAVEC= (u16*)alloc((size_t)1024*2048*2);
  u16*  WQ   = (u16*)alloc((size_t)512*1024*2);
  u16*  PE   = (u16*)alloc((size_t)256*512*2);
  u16*  WINIT= (u16*)alloc((size_t)1024*1024*2);
  u16*  MEANB= (u16*)alloc((size_t)64*1024*2);
  u16*  XC   = (u16*)alloc((size_t)65*64*2816*2);     // 23.4MB
  u16*  ATT  = (u16*)alloc((size_t)64*64*1024*2);     // 8MB
  float* HWT = (float*)alloc((size_t)64*64*1024*4);   // 16MB (per-step)
  float* PLT = (float*)alloc((size_t)64*256*4);       // 64KB
  u16*  CTXBT=(u16*)alloc((size_t)64*256*1024*2);     // 32MB (per-step partials)
  u16*  CTXFT=(u16*)alloc((size_t)64*64*1024*2);      // 8MB (per-step final ctx)
  u16*  Q    = (u16*)alloc((size_t)4096*512*2);
  float* LG  = (float*)alloc((size_t)4096*256*4);
  int*  BAR  = (int*)alloc(4096);
  (void)ws_size; (void)in_sizes; (void)n_in; (void)out_size;  // needs ws >= ~190MB

  hipMemsetAsync(XC, 0, (size_t)64*2816*2, stream);   // XC[0]: embeds+att zero; h by init GEMM
  hipMemsetAsync(BAR, 0, 4096, stream);

  k_cast8<<<32768,256,0,stream>>>(enc, ENC8, (long)64*1024*1024);
  k_cast<<<1024,256,0,stream>>>(W_attvec, WAVEC, (long)1024*2048);
  k_cast<<<256,256,0,stream>>>(W_q2a, WQ, (long)512*1024);
  k_cast<<<64,256,0,stream>>>(prod_emb, PE, (long)256*512);
  k_cast<<<512,256,0,stream>>>(W_init, WINIT, (long)1024*1024);
  k_build_wc<<<5632,256,0,stream>>>(W_ih, W_hh, WC);
  k_wattT<<<4096,256,0,stream>>>(W_att, WAVT);
  k_meanf<<<dim3(64,4),256,0,stream>>>(enc, MEANB);
  k_gemm<2><<<dim3(64,1),256,0,stream>>>(MEANB, 1024L, WINIT, 1024, b_init,
                                         nullptr, 0L, XC + 1792, 2816L);
  k_embed<<<4096,256,0,stream>>>(prod_emb, type_emb, prev_pid, prev_tid, sk_lens, XC);

  k_decoder<<<256,1024,0,stream>>>(ENC8, WC, WAVT, WAVEC, b_ih, b_hh,
                                   XC, ATT, HWT, PLT, CTXBT, CTXFT, src_lens, BAR);

  k_gemm<2><<<dim3(32,64),256,0,stream>>>(ATT, 1024L, WQ, 1024, b_q2a,
                                          nullptr, 0L, Q, 512L);
  k_gemm<3><<<dim3(16,64),256,0,stream>>>(Q, 512L, PE, 512, prod_bias,
                                          LG, 256L, nullptr, 0L);
  k_loss<<<64,256,0,stream>>>(LG, target, sk_lens, out);
}

// Round 12
// 3868.414 us; speedup vs baseline: 1.1615x; 1.1615x over previous
//
#include <hip/hip_runtime.h>
#include <hip/hip_bf16.h>

typedef unsigned short u16;
typedef unsigned char u8;
typedef unsigned int u32;
typedef unsigned long long u64;
typedef __attribute__((ext_vector_type(8))) short short8;
typedef __attribute__((ext_vector_type(8))) u16 ushort8;
typedef __attribute__((ext_vector_type(4))) float f32x4;
typedef __attribute__((ext_vector_type(2))) float f32x2;

__device__ __forceinline__ float bf2f(u16 x){ u32 u=((u32)x)<<16; return __builtin_bit_cast(float,u); }
__device__ __forceinline__ u16 f2bf(float f){ u32 u=__builtin_bit_cast(u32,f); u32 r=(u+0x7fffu+((u>>16)&1u))>>16; return (u16)r; }
__device__ __forceinline__ float sigf(float x){ return 1.f/(1.f+__expf(-x)); }

// coherent STORES only (write-through past L2). Loads are plain; correctness
// from first-touch-after-write (time-indexed buffers).
__device__ __forceinline__ void scf(float* p, float v){
  __hip_atomic_store(p, v, __ATOMIC_RELAXED, __HIP_MEMORY_SCOPE_AGENT);
}
__device__ __forceinline__ void scu16(u16* p, u16 v){
  __hip_atomic_store(p, v, __ATOMIC_RELAXED, __HIP_MEMORY_SCOPE_AGENT);
}
__device__ __forceinline__ int ald(const int* p){
  return __hip_atomic_load(p, __ATOMIC_RELAXED, __HIP_MEMORY_SCOPE_AGENT);
}

// ---------------- prologue kernels ----------------

__global__ __launch_bounds__(256) void k_cast(const float* __restrict__ s, u16* __restrict__ d, long n){
  long i = ((long)blockIdx.x*256 + threadIdx.x)*8;
  if (i >= n) return;
  float4 a = *(const float4*)(s+i);
  float4 b = *(const float4*)(s+i+4);
  ushort8 o;
  o[0]=f2bf(a.x); o[1]=f2bf(a.y); o[2]=f2bf(a.z); o[3]=f2bf(a.w);
  o[4]=f2bf(b.x); o[5]=f2bf(b.y); o[6]=f2bf(b.z); o[7]=f2bf(b.w);
  *(ushort8*)(d+i) = o;
}

// f32 -> OCP e4m3 fp8 (HW cvt)
__global__ __launch_bounds__(256) void k_cast8(const float* __restrict__ s, u8* __restrict__ d, long n){
  long i = ((long)blockIdx.x*256 + threadIdx.x)*8;
  if (i >= n) return;
  float4 a = *(const float4*)(s+i);
  float4 b = *(const float4*)(s+i+4);
  u32 w0 = 0, w1 = 0;
  w0 = __builtin_amdgcn_cvt_pk_fp8_f32(a.x, a.y, w0, false);
  w0 = __builtin_amdgcn_cvt_pk_fp8_f32(a.z, a.w, w0, true);
  w1 = __builtin_amdgcn_cvt_pk_fp8_f32(b.x, b.y, w1, false);
  w1 = __builtin_amdgcn_cvt_pk_fp8_f32(b.z, b.w, w1, true);
  uint2 o; o.x = w0; o.y = w1;
  *(uint2*)(d+i) = o;
}

// x-layout: [a_e(0..511) | t_e(512..767) | att(768..1791) | h(1792..2815)]
__global__ __launch_bounds__(256) void k_build_wc(const float* __restrict__ Wih, const float* __restrict__ Whh,
                                                  u16* __restrict__ WC){
  long i8 = (long)blockIdx.x*256 + threadIdx.x;           // 4096*352
  if (i8 >= (long)4096*352) return;
  int j = (int)(i8/352); int kk = (int)(i8%352)*8;
  const float* src;
  if (kk < 512)        src = Wih + (long)j*1792 + kk;
  else if (kk < 768)   src = Wih + (long)j*1792 + (kk+1024);
  else if (kk < 1792)  src = Wih + (long)j*1792 + (kk-256);
  else                 src = Whh + (long)j*1024 + (kk-1792);
  u16* dst = WC + (long)j*2816 + kk;
  ushort8 o;
  #pragma unroll
  for (int q=0;q<8;++q) o[q] = f2bf(src[q]);
  *(ushort8*)dst = o;
}

__global__ __launch_bounds__(256) void k_wattT(const float* __restrict__ Wa, u16* __restrict__ WT){
  int id = blockIdx.x*256 + threadIdx.x;                  // 1M
  int m = id >> 10, k = id & 1023;
  WT[(long)m*1024 + k] = f2bf(Wa[(long)k*1024 + m]);
}

// mean over S from the original f32 enc
__global__ __launch_bounds__(256) void k_meanf(const float* __restrict__ enc, u16* __restrict__ MEANB){
  int b = blockIdx.x, h = blockIdx.y*256 + threadIdx.x;
  const float* p = enc + ((long)b<<20) + h;
  float s = 0.f;
  for (int ss=0; ss<1024; ++ss) s += p[(long)ss<<10];
  MEANB[b*1024 + h] = f2bf(s * (1.f/1024.f));
}

__global__ __launch_bounds__(256) void k_embed(const float* __restrict__ pemb, const float* __restrict__ temb,
      const int* __restrict__ pid, const int* __restrict__ tid_, const int* __restrict__ slen,
      u16* __restrict__ XC){
  int t = blockIdx.x >> 6, b = blockIdx.x & 63;
  bool valid = (t>0) && (t < slen[b]);
  int pi = pid[b*64 + t], ti = tid_[b*64 + t];
  u16* dst = XC + (long)blockIdx.x*2816;
  for (int kk = threadIdx.x; kk < 768; kk += 256){
    float v = 0.f;
    if (valid) v = (kk<512) ? pemb[(long)pi*512 + kk] : temb[(long)ti*256 + (kk-512)];
    dst[kk] = f2bf(v);
  }
}

// generic small GEMM: out = A[M x K] @ W[N x K]^T (block: 64 rows x 16 cols, 4 waves)
template<int MODE>
__global__ __launch_bounds__(256) void k_gemm(const u16* __restrict__ A, long lda,
      const u16* __restrict__ W, int K, const float* __restrict__ bias,
      float* __restrict__ OF, long ldo, u16* __restrict__ OB1, long ldb1){
  int l = threadIdx.x & 63, w = threadIdx.x >> 6;
  int c = l & 15, g = l >> 4;
  int n0 = blockIdx.x*16, m0 = blockIdx.y*64;
  const u16* ap = A + (long)(m0 + w*16 + c)*lda + g*8;
  const u16* bp = W + (long)(n0 + c)*K + g*8;
  f32x4 acc = {0.f,0.f,0.f,0.f};
  int kit = K >> 5;
  #pragma unroll 4
  for (int kb=0; kb<kit; ++kb){
    short8 av = *(const short8*)(ap + kb*32);
    short8 bv = *(const short8*)(bp + kb*32);
    acc = __builtin_amdgcn_mfma_f32_16x16x32_bf16(av, bv, acc, 0, 0, 0);
  }
  #pragma unroll
  for (int r=0;r<4;++r){
    int row = m0 + w*16 + g*4 + r;
    int col = n0 + c;
    float v = acc[r];
    if (MODE==2){ OB1[(long)row*ldb1 + col] = f2bf(tanhf(v + bias[col])); }
    if (MODE==3){ OF[(long)row*ldo + col] = v + bias[col]; }
  }
}

__global__ __launch_bounds__(256) void k_loss(const float* __restrict__ LG, const int* __restrict__ tgt,
      const int* __restrict__ slen, float* __restrict__ out){
  int b = blockIdx.x;
  int w = threadIdx.x >> 6, l = threadIdx.x & 63;
  int len = slen[b];
  float accum = 0.f;
  for (int t = w; t < 64; t += 4){
    if (t >= len) continue;
    const float* lp = LG + ((long)(t*64 + b))*256;
    float v0=lp[l], v1=lp[l+64], v2=lp[l+128], v3=lp[l+192];
    float mx = fmaxf(fmaxf(v0,v1), fmaxf(v2,v3));
    #pragma unroll
    for (int off=32; off; off>>=1) mx = fmaxf(mx, __shfl_xor(mx, off));
    float s = __expf(v0-mx)+__expf(v1-mx)+__expf(v2-mx)+__expf(v3-mx);
    #pragma unroll
    for (int off=32; off; off>>=1) s += __shfl_xor(s, off);
    float ltg = lp[tgt[b*64 + t]];
    float p = __expf(ltg - mx)/s;
    accum += logf(p + 1e-8f);
  }
  __shared__ float sm[4];
  if (l == 0) sm[w] = accum;
  __syncthreads();
  if (threadIdx.x == 0) out[b] = sm[0]+sm[1]+sm[2]+sm[3];
}

// ---------------- persistent decoder (256 blocks x 1024 threads) ----------------
// Contention-free barrier: arrivals on 16 group counters (no one polls them);
// group-last (via returned prev) bumps master; master-last WRITES 16 release
// lines; waiters (lane 0 only) poll their release line (written once/barrier).
// BAR layout (ints): [0..255] group counters (stride 16); [256] master;
// [320..575] release lines (stride 16).
__device__ __forceinline__ void gbar(int* __restrict__ BAR, int gen){
  int grp = blockIdx.x & 15;
  int prev = __hip_atomic_fetch_add(BAR + grp*16, 1, __ATOMIC_RELAXED, __HIP_MEMORY_SCOPE_AGENT);
  if (prev == gen*16 - 1){
    int p2 = __hip_atomic_fetch_add(BAR + 256, 1, __ATOMIC_RELAXED, __HIP_MEMORY_SCOPE_AGENT);
    if (p2 == gen*16 - 1){
      #pragma unroll
      for (int i=0;i<16;++i)
        __hip_atomic_store(BAR + 320 + i*16, gen, __ATOMIC_RELAXED, __HIP_MEMORY_SCOPE_AGENT);
    }
  }
  while (ald(BAR + 320 + grp*16) < gen)
    __builtin_amdgcn_s_sleep(2);
}

__global__ __launch_bounds__(1024,1) void k_decoder(
      const u8* __restrict__ ENC8, const u16* __restrict__ WC,
      const u16* __restrict__ WAVT, const u16* __restrict__ WAVEC,
      const float* __restrict__ bih, const float* __restrict__ bhh,
      u16* __restrict__ XC, u16* __restrict__ ATT,
      float* __restrict__ HWT, float* __restrict__ PLT,
      u16* __restrict__ CTXBT, const int* __restrict__ src_lens,
      int* __restrict__ BAR){
  const int tid = threadIdx.x;
  const int w = tid >> 6, l = tid & 63, c = l & 15, g = l >> 4;
  const int bx = blockIdx.x;
  int genb = 0;

  __shared__ float smem[12320];                 // 48.1KB, phase-aliased
  f32x4* lacc  = (f32x4*)smem;                  // P1/P2: [16][64] f32x4
  float* s_ctx = smem;                          // P3: [8][1024]
  float* s_ls  = smem + 12288;                  // [16]
  u16*   ldsc  = (u16*)smem;                    // P4: [16][1024] bf16
  f32x4* lacc4 = (f32x4*)(smem + 8192);         // P4: [16][64] f32x4

  // P1 constants
  const int n0 = bx << 2;
  const int jrow = n0 + (c & 3) + ((c >> 2) << 10);
  const float biasj = bih[jrow] + bhh[jrow];
  const int kh = w >> 2, mt = w & 3;
  const int lbase = l & 0x33;
  float creg[4] = {0.f,0.f,0.f,0.f};
  // P2 constants
  const int mt2 = bx & 3, nt2 = bx >> 2;
  // P3 constants (fixed 4 chunks per b)
  const int b3 = bx >> 2, ci3 = bx & 3;
  int len3 = src_lens[b3]; if (len3 < 1) len3 = 1; if (len3 > 1024) len3 = 1024;
  const int chunk3 = (len3 + 3) >> 2;
  int s0 = ci3*chunk3;
  int s1 = s0 + chunk3; if (s1 > len3) s1 = len3;
  const u8* encb = ENC8 + (((long)b3)<<20);
  int lim = s1 - s0 - w;
  int nqv = (lim <= 0) ? 0 : ((lim + 15) >> 4);
  if (nqv > 16) nqv = 16;
  // P4 constants
  const int mt4 = bx & 3, nt4 = bx >> 2;
  const int b16 = tid >> 6, lane64 = tid & 63;

  // ---- pin ENC chunk rows (q<12) in registers ----
  uint4 er[12];
  #pragma unroll
  for (int q=0;q<12;++q){
    int r = s0 + q*16 + w;
    if (r >= s1) r = s0;
    er[q] = *(const uint4*)(encb + ((long)r<<10) + l*16);
  }

  for (int t = 0; t < 64; ++t){
    const u16* XCt = XC + (size_t)t*64*2816;
    u16* XCn = XC + (size_t)(t+1)*64*2816;
    const u16* Hcur = XCn + 1792;
    float* HW   = HWT  + ((size_t)t<<16);
    float* PL   = PLT  + ((size_t)t<<8);
    u16*  CTXB  = CTXBT + ((size_t)t<<18);

    // ---- P1: gates GEMM (split-K x4) + LSTM pointwise; h -> XCn ----
    {
      const u16* ap = XCt + (long)(mt*16 + c)*2816 + kh*704 + g*8;
      const u16* bp = WC  + (long)jrow*2816 + kh*704 + g*8;
      f32x4 acc = {0.f,0.f,0.f,0.f};
      #pragma unroll 11
      for (int kb=0; kb<22; ++kb){
        short8 av = *(const short8*)(ap + kb*32);
        short8 bv = *(const short8*)(bp + kb*32);
        acc = __builtin_amdgcn_mfma_f32_16x16x32_bf16(av, bv, acc, 0, 0, 0);
      }
      lacc[w*64 + l] = acc;
      __syncthreads();
      if (w < 4){
        f32x4 a0 = lacc[w*64 + l];
        f32x4 a1 = lacc[(w+4)*64 + l];
        f32x4 a2 = lacc[(w+8)*64 + l];
        f32x4 a3 = lacc[(w+12)*64 + l];
        #pragma unroll
        for (int r=0;r<4;++r){
          float val = a0[r] + a1[r] + a2[r] + a3[r] + biasj;
          float iv = __shfl(val, lbase);
          float fv = __shfl(val, lbase+4);
          float gv = __shfl(val, lbase+8);
          float ov = __shfl(val, lbase+12);
          if ((l & 12) == 0){
            float cn = sigf(fv)*creg[r] + sigf(iv)*tanhf(gv);
            float hn = sigf(ov)*tanhf(cn);
            creg[r] = cn;
            int b = w*16 + g*4 + r;
            int n = n0 + (l & 3);
            scu16(XCn + (long)b*2816 + 1792 + n, f2bf(hn));
          }
        }
      }
    }
    ++genb;
    __syncthreads();
    if (tid == 0) gbar(BAR, genb);
    __syncthreads();

    // ---- P2: HW = h @ W_att^T (16-way split-K, LDS reduce) ----
    {
      const u16* ap = Hcur + (long)(mt2*16 + c)*2816 + w*64 + g*8;
      const u16* bp = WAVT + (long)(nt2*16 + c)*1024 + w*64 + g*8;
      f32x4 acc = {0.f,0.f,0.f,0.f};
      #pragma unroll
      for (int kb=0; kb<2; ++kb){
        short8 av = *(const short8*)(ap + kb*32);
        short8 bv = *(const short8*)(bp + kb*32);
        acc = __builtin_amdgcn_mfma_f32_16x16x32_bf16(av, bv, acc, 0, 0, 0);
      }
      lacc[w*64 + l] = acc;
      __syncthreads();
      if (w == 0){
        f32x4 rd = lacc[l];
        #pragma unroll
        for (int w2=1; w2<16; ++w2) rd += lacc[w2*64 + l];
        #pragma unroll
        for (int r=0;r<4;++r)
          scf(HW + (long)(mt2*16 + g*4 + r)*1024 + nt2*16 + c, rd[r]);
      }
    }
    ++genb;
    __syncthreads();
    if (tid == 0) gbar(BAR, genb);
    __syncthreads();

    // ---- P3: attention from REGISTERS (max-free exp) ----
    {
      float hw[16], ctx[16];
      const float* hwp = HW + b3*1024 + l*16;
      #pragma unroll
      for (int jj=0;jj<4;++jj){
        float4 v = *(const float4*)(hwp + jj*4);
        hw[4*jj]=v.x; hw[4*jj+1]=v.y; hw[4*jj+2]=v.z; hw[4*jj+3]=v.w;
      }
      #pragma unroll
      for (int jj=0;jj<16;++jj) ctx[jj]=0.f;
      float lsum = 0.f;
      auto proc = [&](uint4 ev){
        float e[16];
        #pragma unroll
        for (int jj=0;jj<4;++jj){
          u32 x = ((const u32*)&ev)[jj];
          f32x2 lo = __builtin_amdgcn_cvt_pk_f32_fp8(x, false);
          f32x2 hi = __builtin_amdgcn_cvt_pk_f32_fp8(x, true);
          e[4*jj]=lo[0]; e[4*jj+1]=lo[1]; e[4*jj+2]=hi[0]; e[4*jj+3]=hi[1];
        }
        float sc = 0.f;
        #pragma unroll
        for (int jj=0;jj<16;++jj) sc += e[jj]*hw[jj];
        #pragma unroll
        for (int off=32; off; off>>=1) sc += __shfl_xor(sc, off);
        float pe = __expf(sc);
        lsum += pe;
        #pragma unroll
        for (int jj=0;jj<16;++jj) ctx[jj] += pe*e[jj];
      };
      #pragma unroll
      for (int q=0;q<12;++q) if (q < nqv) proc(er[q]);
      for (int q=12; q<nqv; ++q){
        uint4 ev = *(const uint4*)(encb + ((long)(s0 + q*16 + w)<<10) + l*16);
        proc(ev);
      }
      if (l == 0) s_ls[w] = lsum;
      if (w < 8){
        #pragma unroll
        for (int jj=0;jj<16;++jj) s_ctx[w*1024 + l*16 + jj] = ctx[jj];
      }
      __syncthreads();
      if (w >= 8){
        #pragma unroll
        for (int jj=0;jj<16;++jj) s_ctx[(w-8)*1024 + l*16 + jj] += ctx[jj];
      }
      __syncthreads();
      {
        float v = 0.f;
        #pragma unroll
        for (int p=0;p<8;++p) v += s_ctx[p*1024 + tid];
        scu16(CTXB + (((long)bx)<<10) + tid, f2bf(v));
      }
      if (tid == 0){
        float L = 0.f;
        #pragma unroll
        for (int q=0;q<16;++q) L += s_ls[q];
        scf(PL + bx, L);
      }
    }
    ++genb;
    __syncthreads();
    if (tid == 0) gbar(BAR, genb);
    __syncthreads();

    // ---- P4: combine 4 partials -> LDS swz + att = tanh([h|ctx]@W_attvec^T) ----
    {
      int b = mt4*16 + b16;
      float L = PL[b*4] + PL[b*4+1] + PL[b*4+2] + PL[b*4+3];
      float inv = (L > 0.f) ? 1.f/L : 0.f;
      const u16* r0 = CTXB + (long)(b*4+0)*1024;
      const u16* r1 = CTXB + (long)(b*4+1)*1024;
      const u16* r2 = CTXB + (long)(b*4+2)*1024;
      const u16* r3 = CTXB + (long)(b*4+3)*1024;
      const int swz = (b16 & 7) << 3;
      #pragma unroll
      for (int q=0;q<2;++q){
        int mcol8 = (lane64 + q*64)*8;
        ushort8 v0 = *(const ushort8*)(r0 + mcol8);
        ushort8 v1 = *(const ushort8*)(r1 + mcol8);
        ushort8 v2 = *(const ushort8*)(r2 + mcol8);
        ushort8 v3 = *(const ushort8*)(r3 + mcol8);
        ushort8 o;
        #pragma unroll
        for (int j=0;j<8;++j)
          o[j] = f2bf((bf2f(v0[j]) + bf2f(v1[j]) + bf2f(v2[j]) + bf2f(v3[j])) * inv);
        *(ushort8*)(ldsc + ((b16*1024 + mcol8) ^ swz)) = o;
      }
      __syncthreads();
      f32x4 acc = {0.f,0.f,0.f,0.f};
      const int koff = (w < 8) ? w*128 : 1024 + (w-8)*128;
      const u16* bp = WAVEC + (long)(nt4*16 + c)*2048 + koff + g*8;
      if (w < 8){
        const u16* ap = Hcur + (long)(mt4*16 + c)*2816 + w*128 + g*8;
        #pragma unroll
        for (int kb=0; kb<4; ++kb){
          short8 av = *(const short8*)(ap + kb*32);
          short8 bv = *(const short8*)(bp + kb*32);
          acc = __builtin_amdgcn_mfma_f32_16x16x32_bf16(av, bv, acc, 0, 0, 0);
        }
      } else {
        const int cswz = (c & 7) << 3;
        const int kbase = c*1024 + (w-8)*128 + g*8;
        #pragma unroll
        for (int kb=0; kb<4; ++kb){
          short8 av = *(const short8*)(ldsc + ((kbase + kb*32) ^ cswz));
          short8 bv = *(const short8*)(bp + kb*32);
          acc = __builtin_amdgcn_mfma_f32_16x16x32_bf16(av, bv, acc, 0, 0, 0);
        }
      }
      lacc4[w*64 + l] = acc;
      __syncthreads();
      if (w == 0){
        f32x4 rd = lacc4[l];
        #pragma unroll
        for (int w2=1; w2<16; ++w2) rd += lacc4[w2*64 + l];
        #pragma unroll
        for (int r=0;r<4;++r){
          int b_ = mt4*16 + g*4 + r;
          int col = nt4*16 + c;
          u16 x = f2bf(tanhf(rd[r]));
          scu16(XCn + (long)b_*2816 + 768 + col, x);
          ATT[((long)t*64 + b_)*1024 + col] = x;
        }
      }
    }
    ++genb;
    __syncthreads();
    if (tid == 0) gbar(BAR, genb);
    __syncthreads();
  }
}

extern "C" void kernel_launch(void* const* d_in, const int* in_sizes, int n_in,
                              void* d_out, int out_size, void* d_ws, size_t ws_size,
                              hipStream_t stream){
  const float* enc      = (const float*)d_in[0];
  const float* W_ih     = (const float*)d_in[1];
  const float* b_ih     = (const float*)d_in[2];
  const float* W_hh     = (const float*)d_in[3];
  const float* b_hh     = (const float*)d_in[4];
  const float* W_att    = (const float*)d_in[5];
  const float* W_attvec = (const float*)d_in[6];
  const float* W_init   = (const float*)d_in[7];
  const float* b_init   = (const float*)d_in[8];
  const float* W_q2a    = (const float*)d_in[9];
  const float* b_q2a    = (const float*)d_in[10];
  const float* prod_emb = (const float*)d_in[11];
  const float* prod_bias= (const float*)d_in[12];
  const float* type_emb = (const float*)d_in[13];
  const int* prev_pid   = (const int*)d_in[14];
  const int* prev_tid   = (const int*)d_in[15];
  const int* target     = (const int*)d_in[16];
  const int* sk_lens    = (const int*)d_in[17];
  const int* src_lens   = (const int*)d_in[18];
  float* out = (float*)d_out;

  char* ws = (char*)d_ws;
  size_t o = 0;
  auto alloc = [&](size_t bytes)->char*{ char* p = ws + o; o += (bytes + 255) & ~(size_t)255; return p; };
  u8*   ENC8 = (u8*)alloc((size_t)64*1024*1024);      // 64MB fp8
  u16*  WC   = (u16*)alloc((size_t)4096*2816*2);      // 22.5MB
  u16*  WAVT = (u16*)alloc((size_t)1024*1024*2);
  u16*  WAVEC= (u16*)alloc((size_t)1024*2048*2);
  u16*  WQ   = (u16*)alloc((size_t)512*1024*2);
  u16*  PE   = (u16*)alloc((size_t)256*512*2);
  u16*  WINIT= (u16*)alloc((size_t)1024*1024*2);
  u16*  MEANB= (u16*)alloc((size_t)64*1024*2);
  u16*  XC   = (u16*)alloc((size_t)65*64*2816*2);     // 23.4MB
  u16*  ATT  = (u16*)alloc((size_t)64*64*1024*2);     // 8MB
  float* HWT = (float*)alloc((size_t)64*64*1024*4);   // 16MB (per-step)
  float* PLT = (float*)alloc((size_t)64*256*4);       // 64KB
  u16*  CTXBT=(u16*)alloc((size_t)64*256*1024*2);     // 32MB (per-step partials)
  u16*  Q    = (u16*)alloc((size_t)4096*512*2);
  float* LG  = (float*)alloc((size_t)4096*256*4);
  int*  BAR  = (int*)alloc(4096);
  (void)ws_size; (void)in_sizes; (void)n_in; (void)out_size;  // needs ws >= ~180MB

  hipMemsetAsync(XC, 0, (size_t)64*2816*2, stream);   // XC[0]: embeds+att zero; h by init GEMM
  hipMemsetAsync(BAR, 0, 4096, stream);

  k_cast8<<<32768,256,0,stream>>>(enc, ENC8, (long)64*1024*1024);
  k_cast<<<1024,256,0,stream>>>(W_attvec, WAVEC, (long)1024*2048);
  k_cast<<<256,256,0,stream>>>(W_q2a, WQ, (long)512*1024);
  k_cast<<<64,256,0,stream>>>(prod_emb, PE, (long)256*512);
  k_cast<<<512,256,0,stream>>>(W_init, WINIT, (long)1024*1024);
  k_build_wc<<<5632,256,0,stream>>>(W_ih, W_hh, WC);
  k_wattT<<<4096,256,0,stream>>>(W_att, WAVT);
  k_meanf<<<dim3(64,4),256,0,stream>>>(enc, MEANB);
  k_gemm<2><<<dim3(64,1),256,0,stream>>>(MEANB, 1024L, WINIT, 1024, b_init,
                                         nullptr, 0L, XC + 1792, 2816L);
  k_embed<<<4096,256,0,stream>>>(prod_emb, type_emb, prev_pid, prev_tid, sk_lens, XC);

  k_decoder<<<256,1024,0,stream>>>(ENC8, WC, WAVT, WAVEC, b_ih, b_hh,
                                   XC, ATT, HWT, PLT, CTXBT, src_lens, BAR);

  k_gemm<2><<<dim3(32,64),256,0,stream>>>(ATT, 1024L, WQ, 1024, b_q2a,
                                          nullptr, 0L, Q, 512L);
  k_gemm<3><<<dim3(16,64),256,0,stream>>>(Q, 512L, PE, 512, prod_bias,
                                          LG, 256L, nullptr, 0L);
  k_loss<<<64,256,0,stream>>>(LG, target, sk_lens, out);
}